// Round 7
// baseline (149.924 us; speedup 1.0000x reference)
//
#include <hip/hip_runtime.h>
#include <math.h>

#define NQ 12
#define DIM 4096
#define NL 4
#define THREADS 256
#define SWZC(e) ((e) ^ (((e) >> 3) & 14) ^ (((e) >> 7) & 15))
#define WAVEFENCE() { __builtin_amdgcn_wave_barrier(); __builtin_amdgcn_sched_barrier(0); }

typedef float v2f __attribute__((ext_vector_type(2)));
typedef float v4f __attribute__((ext_vector_type(4)));

__device__ __forceinline__ v2f pkfma(v2f a, v2f b, v2f c) {
    v2f d; asm("v_pk_fma_f32 %0, %1, %2, %3" : "=v"(d) : "v"(a), "v"(b), "v"(c)); return d;
}
__device__ __forceinline__ v2f pkmul(v2f a, v2f b) {
    v2f d; asm("v_pk_mul_f32 %0, %1, %2" : "=v"(d) : "v"(a), "v"(b)); return d;
}
__device__ __forceinline__ v2f pkadd(v2f a, v2f b) {
    v2f d; asm("v_pk_add_f32 %0, %1, %2" : "=v"(d) : "v"(a), "v"(b)); return d;
}
__device__ __forceinline__ float2 cmulS(float2 a, float2 b) {
    return make_float2(fmaf(a.x, b.x, -a.y * b.y), fmaf(a.x, b.y, a.y * b.x));
}

struct C4 { v2f r, i, ni, nr; };   // broadcast (re,re),(im,im),(-im,-im),(-re,-re)

#define CMUL4(orE, orI, KR, KNI, KI, xre, xim) \
    { orE = pkfma(KNI, xim, pkmul(KR, xre)); orI = pkfma(KI, xre, pkmul(KR, xim)); }
#define CMAC4(orE, orI, KR, KNI, KI, xre, xim) \
    { orE = pkfma(KR, xre, pkfma(KNI, xim, orE)); orI = pkfma(KR, xim, pkfma(KI, xre, orI)); }

// SU(2) 2-stage 4x4 pair-gate; even-CNOT baked in (outputs C<-y3, D<-y2).
#define QUADBODY(A_, B_, C_, D_) { \
    v2f z0r,z0i,z1r,z1i,z2r,z2i,z3r,z3i; \
    CMUL4(z0r,z0i, la.r, la.ni, la.i, sre[A_], sim[A_]); CMAC4(z0r,z0i, lb.r, lb.ni, lb.i, sre[B_], sim[B_]); \
    CMUL4(z1r,z1i, lb.nr, lb.ni, lb.i, sre[A_], sim[A_]); CMAC4(z1r,z1i, la.r, la.i, la.ni, sre[B_], sim[B_]); \
    CMUL4(z2r,z2i, la.r, la.ni, la.i, sre[C_], sim[C_]); CMAC4(z2r,z2i, lb.r, lb.ni, lb.i, sre[D_], sim[D_]); \
    CMUL4(z3r,z3i, lb.nr, lb.ni, lb.i, sre[C_], sim[C_]); CMAC4(z3r,z3i, la.r, la.i, la.ni, sre[D_], sim[D_]); \
    v2f y0r,y0i,y1r,y1i,y2r,y2i,y3r,y3i; \
    CMUL4(y0r,y0i, ha.r, ha.ni, ha.i, z0r, z0i); CMAC4(y0r,y0i, hb.r, hb.ni, hb.i, z2r, z2i); \
    CMUL4(y1r,y1i, ha.r, ha.ni, ha.i, z1r, z1i); CMAC4(y1r,y1i, hb.r, hb.ni, hb.i, z3r, z3i); \
    CMUL4(y2r,y2i, hb.nr, hb.ni, hb.i, z0r, z0i); CMAC4(y2r,y2i, ha.r, ha.i, ha.ni, z2r, z2i); \
    CMUL4(y3r,y3i, hb.nr, hb.ni, hb.i, z1r, z1i); CMAC4(y3r,y3i, ha.r, ha.i, ha.ni, z3r, z3i); \
    sre[A_]=y0r; sim[A_]=y0i; sre[B_]=y1r; sim[B_]=y1i; \
    sre[C_]=y3r; sim[C_]=y3i; sre[D_]=y2r; sim[D_]=y2i; }

#define RUNQUADS_HI QUADBODY(0,4,8,12) QUADBODY(1,5,9,13) QUADBODY(2,6,10,14) QUADBODY(3,7,11,15)
#define RUNQUADS_LO QUADBODY(0,1,2,3) QUADBODY(4,5,6,7) QUADBODY(8,9,10,11) QUADBODY(12,13,14,15)

// passes over BOTH circuit-pair streams with one coefficient load
__device__ __forceinline__ void pass_hi2(v2f* r0, v2f* i0, v2f* r1, v2f* i1, const v2f (*U)[4]) {
    C4 la={U[0][0],U[0][1],U[0][2],U[0][3]}, lb={U[1][0],U[1][1],U[1][2],U[1][3]},
       ha={U[2][0],U[2][1],U[2][2],U[2][3]}, hb={U[3][0],U[3][1],U[3][2],U[3][3]};
    { v2f* sre=r0; v2f* sim=i0; RUNQUADS_HI }
    { v2f* sre=r1; v2f* sim=i1; RUNQUADS_HI }
}
__device__ __forceinline__ void pass_lo2(v2f* r0, v2f* i0, v2f* r1, v2f* i1, const v2f (*U)[4]) {
    C4 la={U[0][0],U[0][1],U[0][2],U[0][3]}, lb={U[1][0],U[1][1],U[1][2],U[1][3]},
       ha={U[2][0],U[2][1],U[2][2],U[2][3]}, hb={U[3][0],U[3][1],U[3][2],U[3][3]};
    { v2f* sre=r0; v2f* sim=i0; RUNQUADS_LO }
    { v2f* sre=r1; v2f* sim=i1; RUNQUADS_LO }
}

__device__ __forceinline__ v4f pack4(v2f a, v2f b) { v4f t; t[0]=a[0]; t[1]=a[1]; t[2]=b[0]; t[3]=b[1]; return t; }

__global__ __launch_bounds__(THREADS, 2)
void vqc_kernel(const float* __restrict__ features,
                const float* __restrict__ theta,
                const float* __restrict__ alpha,
                float* __restrict__ out)
{
    __shared__ v4f scr4[DIM];             // 64 KB: one plane (re OR im) of 4 packed circuits
    __shared__ v2f Upk[24][4][4];         // 3 KB coeff quads (broadcast)
    __shared__ v4f red[12 * 4];
    __shared__ float wez[12];

    // build-phase tables aliased into scr4 (dead before first transition store)
    float2* cs = (float2*)scr4;                                     // [0,1152)
    float2 (*U48)[4] = (float2(*)[4])((char*)scr4 + 1152);          // [1152,2688)
    float2 (*enc)[2] = (float2(*)[2])((char*)scr4 + 2688);          // [2688,3456) 48x2 f2
    float2 (*pairT)[4] = (float2(*)[4])((char*)scr4 + 3456);        // [3456,4224) 24x4 f2
    float2* loc = (float2*)((char*)scr4 + 4224);                    // [4224,4736) 64 f2

    const int tid = threadIdx.x;
    const bool special = (blockIdx.x == 0);   // shared h_angle_rx circuit (|+>^12 up to phase)
    const int gBase = special ? 0 : 4 * ((int)blockIdx.x - 1);

    // ---- stage 1: theta sincos + encoding states (4 circuits) ----
    if (tid < NL * NQ * 3) {
        float s, c; sincosf(0.5f * theta[tid], &s, &c);
        cs[tid] = make_float2(c, s);
    }
    if (tid >= 160 && tid < 208) {
        int c_ = (tid - 160) / 12, q = (tid - 160) % 12;
        const float r_ = 0.70710678118654752f;
        float2 a0, a1;
        if (special) { a0 = make_float2(r_, 0.f); a1 = a0; }
        else {
            int g = gBase + c_;
            int esl = g % 3, b = g / 3;
            float f = features[b * NQ + q];
            float s, c; sincosf(0.5f * f, &s, &c);
            if (esl == 0)      { a0 = make_float2(c, 0.f); a1 = make_float2(0.f, -s); }          // angle_rx
            else if (esl == 1) { a0 = make_float2(c, 0.f); a1 = make_float2(s, 0.f); }           // angle_ry
            else               { a0 = make_float2((c-s)*r_, 0.f); a1 = make_float2((c+s)*r_, 0.f); } // h_angle_ry
        }
        enc[c_ * NQ + q][0] = a0; enc[c_ * NQ + q][1] = a1;
    }
    __syncthreads();

    // ---- stage 2: fused U = RZ*RY*RX + pair tables (4 circuits) ----
    if (tid < NL * NQ) {
        float c0 = cs[tid*3+0].x, s0 = cs[tid*3+0].y;
        float c1 = cs[tid*3+1].x, s1 = cs[tid*3+1].y;
        float c2 = cs[tid*3+2].x, s2 = cs[tid*3+2].y;
        float2 a00 = make_float2( c1*c0,  s1*s0);
        float2 a01 = make_float2(-s1*c0, -c1*s0);
        float2 a10 = make_float2( s1*c0, -c1*s0);
        float2 a11 = make_float2( c1*c0, -s1*s0);
        float2 ep = make_float2(c2, -s2), em = make_float2(c2, s2);
        U48[tid][0] = cmulS(ep, a00); U48[tid][1] = cmulS(ep, a01);
        U48[tid][2] = cmulS(em, a10); U48[tid][3] = cmulS(em, a11);
    }
    if (tid >= 64 && tid < 160) {
        int x = tid - 64;
        int c_ = x / 24, y = x % 24, p = y >> 2, v = y & 3;
        pairT[c_ * 6 + p][v] = cmulS(enc[c_*NQ + 2*p][v >> 1], enc[c_*NQ + 2*p + 1][v & 1]);
    }
    __syncthreads();

    // ---- stage 3: packed SU(2) coeff quads + local product tables ----
    for (int idx = tid; idx < 384; idx += THREADS) {
        int p = idx >> 4, rest = idx & 15, c = rest >> 2, comp = rest & 3;
        int l = p / 6, m = p % 6;
        int q = (c < 2) ? (2*m + 1) : (2*m);
        float2 u = U48[l*NQ + q][c & 1];
        float xv = (comp == 0) ? u.x : (comp == 1) ? u.y : (comp == 2) ? -u.y : -u.x;
        v2f vv = {xv, xv};
        Upk[p][c][comp] = vv;
    }
    if (tid >= 192 && tid < 256) {
        int x = tid - 192; int c_ = x >> 4, j = x & 15;
        loc[c_ * 16 + j] = cmulS(pairT[c_*6 + 4][j >> 2], pairT[c_*6 + 5][j & 3]);
    }
    __syncthreads();

    // ---- build product state into LA registers: 4 circuits (two v2f streams) ----
    v2f r0[16], i0[16], r1[16], i1[16];
    {
        int t = tid;
        float2 pre[4];
        #pragma unroll
        for (int c = 0; c < 4; ++c)
            pre[c] = cmulS(cmulS(pairT[c*6+0][(t>>6)&3], pairT[c*6+1][(t>>4)&3]),
                           cmulS(pairT[c*6+2][(t>>2)&3], pairT[c*6+3][t&3]));
        #pragma unroll
        for (int j = 0; j < 16; ++j) {
            float2 aA = cmulS(pre[0], loc[j]);
            float2 aB = cmulS(pre[1], loc[16 + j]);
            float2 aC = cmulS(pre[2], loc[32 + j]);
            float2 aD = cmulS(pre[3], loc[48 + j]);
            v2f ra = {aA.x, aB.x}; v2f ia = {aA.y, aB.y};
            v2f rb = {aC.x, aD.x}; v2f ib = {aC.y, aD.y};
            r0[j] = ra; i0[j] = ia; r1[j] = rb; i1[j] = ib;
        }
    }
    __syncthreads();   // tables (aliased in scr4) dead before first transition store

    const int ba = SWZC(tid << 4);
    const int bb = SWZC((((tid >> 4) << 8) | (tid & 15)));
    const int bc = SWZC(tid);
    const int sx = (tid << 4) ^ ((tid & 1) << 3) ^ (((tid >> 2) & 1) << 5)
                             ^ (((tid >> 4) & 1) << 7) ^ (((tid >> 6) & 1) << 9);
    const int bs = SWZC(sx);

    // ---- 4 variational layers ----
    #pragma unroll 1
    for (int l = 0; l < NL; ++l) {
        // LA: P4 (bits 3,2), P5 (bits 1,0)
        pass_hi2(r0, i0, r1, i1, Upk[l*6 + 4]);
        pass_lo2(r0, i0, r1, i1, Upk[l*6 + 5]);
        // T_AB: wave-local, plane-chunked (in-order DS per wave handles WAR)
        WAVEFENCE();
        #pragma unroll
        for (int j = 0; j < 16; ++j) scr4[ba ^ j] = pack4(r0[j], r1[j]);
        WAVEFENCE();
        #pragma unroll
        for (int j = 0; j < 16; ++j) { v4f t = scr4[bb ^ SWZC(j << 4)]; v2f a={t[0],t[1]}, b={t[2],t[3]}; r0[j]=a; r1[j]=b; }
        WAVEFENCE();
        #pragma unroll
        for (int j = 0; j < 16; ++j) scr4[ba ^ j] = pack4(i0[j], i1[j]);
        WAVEFENCE();
        #pragma unroll
        for (int j = 0; j < 16; ++j) { v4f t = scr4[bb ^ SWZC(j << 4)]; v2f a={t[0],t[1]}, b={t[2],t[3]}; i0[j]=a; i1[j]=b; }
        WAVEFENCE();
        // LB: P2 (bits 7,6), P3 (bits 5,4)
        pass_hi2(r0, i0, r1, i1, Upk[l*6 + 2]);
        pass_lo2(r0, i0, r1, i1, Upk[l*6 + 3]);
        // T_BC: store own-quarter (bb), gather cross (bc), plane-chunked
        WAVEFENCE();
        #pragma unroll
        for (int j = 0; j < 16; ++j) scr4[bb ^ SWZC(j << 4)] = pack4(r0[j], r1[j]);
        __syncthreads();
        #pragma unroll
        for (int j = 0; j < 16; ++j) { v4f t = scr4[bc ^ SWZC(j << 8)]; v2f a={t[0],t[1]}, b={t[2],t[3]}; r0[j]=a; r1[j]=b; }
        __syncthreads();
        #pragma unroll
        for (int j = 0; j < 16; ++j) scr4[bb ^ SWZC(j << 4)] = pack4(i0[j], i1[j]);
        __syncthreads();
        #pragma unroll
        for (int j = 0; j < 16; ++j) { v4f t = scr4[bc ^ SWZC(j << 8)]; v2f a={t[0],t[1]}, b={t[2],t[3]}; i0[j]=a; i1[j]=b; }
        // LC: P0 (bits 11,10), P1 (bits 9,8) — split sync (drain all gathers before T_CA stores)
        pass_hi2(r0, i0, r1, i1, Upk[l*6 + 0]);
        __syncthreads();
        pass_lo2(r0, i0, r1, i1, Upk[l*6 + 1]);
        if (l < NL - 1) {
            // T_CA: store cross (bc), gather sigma-folded own-quarter (bs)
            #pragma unroll
            for (int j = 0; j < 16; ++j) scr4[bc ^ SWZC(j << 8)] = pack4(r0[j], r1[j]);
            __syncthreads();
            #pragma unroll
            for (int j = 0; j < 16; ++j) { int a_ = bs ^ (j ^ ((j >> 1) & 2)); v4f t = scr4[a_]; v2f a={t[0],t[1]}, b={t[2],t[3]}; r0[j]=a; r1[j]=b; }
            __syncthreads();
            #pragma unroll
            for (int j = 0; j < 16; ++j) scr4[bc ^ SWZC(j << 8)] = pack4(i0[j], i1[j]);
            __syncthreads();
            #pragma unroll
            for (int j = 0; j < 16; ++j) { int a_ = bs ^ (j ^ ((j >> 1) & 2)); v4f t = scr4[a_]; v2f a={t[0],t[1]}, b={t[2],t[3]}; i0[j]=a; i1[j]=b; }
            WAVEFENCE();   // next scr4 write (T_AB of l+1) is own-quarter: wave-local WAR
        }
    }

    // ---- measurement in LC, layer-3 sigma folded into sign indices ----
    v2f s0a={0,0}, s1a={0,0}, s2a={0,0}, s3a={0,0}, pa={0,0};
    v2f s0b={0,0}, s1b={0,0}, s2b={0,0}, s3b={0,0}, pb={0,0};
    {
        const v2f MONE = {-1.f, -1.f};
        #pragma unroll
        for (int j = 0; j < 16; ++j) {
            v2f p0 = pkfma(i0[j], i0[j], pkmul(r0[j], r0[j]));
            v2f p1 = pkfma(i1[j], i1[j], pkmul(r1[j], r1[j]));
            pa = pkadd(pa, p0); pb = pkadd(pb, p1);
            if (j & 8) { s0a = pkfma(p0, MONE, s0a); s0b = pkfma(p1, MONE, s0b); } else { s0a = pkadd(s0a, p0); s0b = pkadd(s0b, p1); }
            if (j & 4) { s1a = pkfma(p0, MONE, s1a); s1b = pkfma(p1, MONE, s1b); } else { s1a = pkadd(s1a, p0); s1b = pkadd(s1b, p1); }
            if ((((j >> 1) ^ (j >> 2)) & 1)) { s2a = pkfma(p0, MONE, s2a); s2b = pkfma(p1, MONE, s2b); } else { s2a = pkadd(s2a, p0); s2b = pkadd(s2b, p1); }
            if (j & 1) { s3a = pkfma(p0, MONE, s3a); s3b = pkfma(p1, MONE, s3b); } else { s3a = pkadd(s3a, p0); s3b = pkadd(s3b, p1); }
        }
    }
    v2f va[12], vb[12];
    {
        int t = tid;
        int mt = t ^ ((t >> 1) & 0xAA);
        va[0]=s0a; va[1]=s1a; va[2]=s2a; va[3]=s3a;
        vb[0]=s0b; vb[1]=s1b; vb[2]=s2b; vb[3]=s3b;
        va[4] = ((t >> 7) & 1) ? -s3a : s3a;  vb[4] = ((t >> 7) & 1) ? -s3b : s3b;
        #pragma unroll
        for (int q = 5; q < 12; ++q) {
            int bit = (mt >> (11 - q)) & 1;
            va[q] = bit ? -pa : pa;  vb[q] = bit ? -pb : pb;
        }
    }
    const int lane = tid & 63, wv = tid >> 6;
    #pragma unroll
    for (int q = 0; q < 12; ++q) {
        v4f v = pack4(va[q], vb[q]);
        #pragma unroll
        for (int mm = 32; mm >= 1; mm >>= 1) {
            v[0] += __shfl_xor(v[0], mm, 64);
            v[1] += __shfl_xor(v[1], mm, 64);
            v[2] += __shfl_xor(v[2], mm, 64);
            v[3] += __shfl_xor(v[3], mm, 64);
        }
        if (lane == 0) red[q * 4 + wv] = v;
    }
    __syncthreads();

    if (tid < 12) {
        v4f v = red[tid*4+0] + red[tid*4+1] + red[tid*4+2] + red[tid*4+3];
        float A0 = alpha[0], A1 = alpha[1], A2 = alpha[2], A3 = alpha[3];
        float mx = fmaxf(fmaxf(A0, A1), fmaxf(A2, A3));
        float E0 = expf(A0-mx), E1 = expf(A1-mx), E2 = expf(A2-mx), E3 = expf(A3-mx);
        float den = E0 + E1 + E2 + E3;
        if (special) {
            wez[tid] = (E2 / den) * v[0];
        } else {
            #pragma unroll
            for (int c = 0; c < 4; ++c) {
                int g = gBase + c;
                int esl = g % 3, b = g / 3;
                float w = ((esl == 0) ? E0 : (esl == 1) ? E1 : E3) / den;
                atomicAdd(out + b * NQ + tid, w * v[c]);
            }
        }
    }
    if (special) {
        __syncthreads();
        for (int bb2 = tid; bb2 < 1024; bb2 += THREADS) {
            #pragma unroll
            for (int q = 0; q < NQ; ++q)
                atomicAdd(out + bb2 * NQ + q, wez[q]);
        }
    }
}

extern "C" void kernel_launch(void* const* d_in, const int* in_sizes, int n_in,
                              void* d_out, int out_size, void* d_ws, size_t ws_size,
                              hipStream_t stream) {
    const float* features = (const float*)d_in[0];
    const float* theta    = (const float*)d_in[1];
    const float* alpha    = (const float*)d_in[2];
    float* out = (float*)d_out;

    hipMemsetAsync(out, 0, (size_t)out_size * sizeof(float), stream);
    // block 0 = shared h_angle_rx circuit; blocks 1..768 = 4 regular circuits each
    vqc_kernel<<<dim3(769), THREADS, 0, stream>>>(features, theta, alpha, out);
}

// Round 8
// 140.630 us; speedup vs baseline: 1.0661x; 1.0661x over previous
//
#include <hip/hip_runtime.h>
#include <math.h>

#define NQ 12
#define DIM 4096
#define NL 4
#define THREADS 256

typedef float v2f __attribute__((ext_vector_type(2)));
typedef float v4f __attribute__((ext_vector_type(4)));

__device__ __forceinline__ v2f pkfma(v2f a, v2f b, v2f c) {
    v2f d; asm("v_pk_fma_f32 %0, %1, %2, %3" : "=v"(d) : "v"(a), "v"(b), "v"(c)); return d;
}
__device__ __forceinline__ v2f pkmul(v2f a, v2f b) {
    v2f d; asm("v_pk_mul_f32 %0, %1, %2" : "=v"(d) : "v"(a), "v"(b)); return d;
}
__device__ __forceinline__ v2f pkadd(v2f a, v2f b) {
    v2f d; asm("v_pk_add_f32 %0, %1, %2" : "=v"(d) : "v"(a), "v"(b)); return d;
}
__device__ __forceinline__ float2 cmulS(float2 a, float2 b) {
    return make_float2(fmaf(a.x, b.x, -a.y * b.y), fmaf(a.x, b.y, a.y * b.x));
}

// odd-CNOT ladder permutation (XOR-linear involution) on 12-bit index
__device__ __forceinline__ int sigp(int i) { return i ^ ((i >> 1) & 0x2AA); }
// 16B-amp address swizzle: XOR upper bits into low 3 -> uniform 8-way bank spread
// for all three window gather patterns (A: i=16t+j, B: i=(t&0xF0)<<4|j<<4|(t&15), C: i=j<<8|t)
__device__ __forceinline__ int swz(int i) { return i ^ ((i >> 3) & 7) ^ ((i >> 6) & 7) ^ ((i >> 9) & 7); }

struct C4 { v2f r, i, ni, nr; };   // broadcast (re,re),(im,im),(-im,-im),(-re,-re)

#define CMUL4(orE, orI, KR, KNI, KI, xre, xim) \
    { orE = pkfma(KNI, xim, pkmul(KR, xre)); orI = pkfma(KI, xre, pkmul(KR, xim)); }
#define CMAC4(orE, orI, KR, KNI, KI, xre, xim) \
    { orE = pkfma(KR, xre, pkfma(KNI, xim, orE)); orI = pkfma(KR, xim, pkfma(KI, xre, orI)); }

// SU(2) 2-stage 4x4 pair-gate; even-CNOT baked in (outputs C<-y3, D<-y2).
#define QUADBODY(A_, B_, C_, D_) { \
    v2f z0r,z0i,z1r,z1i,z2r,z2i,z3r,z3i; \
    CMUL4(z0r,z0i, la.r, la.ni, la.i, sre[A_], sim[A_]); CMAC4(z0r,z0i, lb.r, lb.ni, lb.i, sre[B_], sim[B_]); \
    CMUL4(z1r,z1i, lb.nr, lb.ni, lb.i, sre[A_], sim[A_]); CMAC4(z1r,z1i, la.r, la.i, la.ni, sre[B_], sim[B_]); \
    CMUL4(z2r,z2i, la.r, la.ni, la.i, sre[C_], sim[C_]); CMAC4(z2r,z2i, lb.r, lb.ni, lb.i, sre[D_], sim[D_]); \
    CMUL4(z3r,z3i, lb.nr, lb.ni, lb.i, sre[C_], sim[C_]); CMAC4(z3r,z3i, la.r, la.i, la.ni, sre[D_], sim[D_]); \
    v2f y0r,y0i,y1r,y1i,y2r,y2i,y3r,y3i; \
    CMUL4(y0r,y0i, ha.r, ha.ni, ha.i, z0r, z0i); CMAC4(y0r,y0i, hb.r, hb.ni, hb.i, z2r, z2i); \
    CMUL4(y1r,y1i, ha.r, ha.ni, ha.i, z1r, z1i); CMAC4(y1r,y1i, hb.r, hb.ni, hb.i, z3r, z3i); \
    CMUL4(y2r,y2i, hb.nr, hb.ni, hb.i, z0r, z0i); CMAC4(y2r,y2i, ha.r, ha.i, ha.ni, z2r, z2i); \
    CMUL4(y3r,y3i, hb.nr, hb.ni, hb.i, z1r, z1i); CMAC4(y3r,y3i, ha.r, ha.i, ha.ni, z3r, z3i); \
    sre[A_]=y0r; sim[A_]=y0i; sre[B_]=y1r; sim[B_]=y1i; \
    sre[C_]=y3r; sim[C_]=y3i; sre[D_]=y2r; sim[D_]=y2i; }

__device__ __forceinline__ void pass_hi(v2f* sre, v2f* sim, const v2f (*U)[4]) {
    C4 la={U[0][0],U[0][1],U[0][2],U[0][3]}, lb={U[1][0],U[1][1],U[1][2],U[1][3]},
       ha={U[2][0],U[2][1],U[2][2],U[2][3]}, hb={U[3][0],U[3][1],U[3][2],U[3][3]};
    QUADBODY(0,4,8,12) QUADBODY(1,5,9,13) QUADBODY(2,6,10,14) QUADBODY(3,7,11,15)
}
__device__ __forceinline__ void pass_lo(v2f* sre, v2f* sim, const v2f (*U)[4]) {
    C4 la={U[0][0],U[0][1],U[0][2],U[0][3]}, lb={U[1][0],U[1][1],U[1][2],U[1][3]},
       ha={U[2][0],U[2][1],U[2][2],U[2][3]}, hb={U[3][0],U[3][1],U[3][2],U[3][3]};
    QUADBODY(0,1,2,3) QUADBODY(4,5,6,7) QUADBODY(8,9,10,11) QUADBODY(12,13,14,15)
}

__device__ __forceinline__ v4f pack4(v2f a, v2f b) { v4f t; t[0]=a[0]; t[1]=a[1]; t[2]=b[0]; t[3]=b[1]; return t; }

__global__ __launch_bounds__(THREADS, 2)
void vqc_kernel(const float* __restrict__ features,
                const float* __restrict__ theta,
                const float* __restrict__ alpha,
                float* __restrict__ out)
{
    __shared__ v4f st[DIM];               // 64 KB state: (reA,reB,imA,imB) per amp, swizzled
    __shared__ float2 cs[NL * NQ * 3];    // 1.1 KB
    __shared__ float2 U48[NL * NQ][4];    // 1.5 KB
    __shared__ float2 enc[2 * NQ][2];     // 0.75 KB
    __shared__ float2 pairT[12][4];       // 0.75 KB
    __shared__ float2 loc[32];            // 0.5 KB
    __shared__ v2f Upk[24][4][4];         // 3 KB coeff quads
    __shared__ v2f red[12 * 4];
    __shared__ float wez[12];

    const int tid = threadIdx.x;
    const bool special = (blockIdx.x == 0);   // shared h_angle_rx circuit (|+>^12 up to phase)
    const int gA = special ? 0 : 2 * ((int)blockIdx.x - 1);
    const int gB = gA + 1;

    // ---- stage 1: theta sincos + encoding states (2 circuits) ----
    if (tid < NL * NQ * 3) {
        float s, c; sincosf(0.5f * theta[tid], &s, &c);
        cs[tid] = make_float2(c, s);
    }
    if (tid >= 160 && tid < 184) {
        int c_ = (tid - 160) / 12, q = (tid - 160) % 12;
        const float r_ = 0.70710678118654752f;
        float2 a0, a1;
        if (special) { a0 = make_float2(r_, 0.f); a1 = a0; }
        else {
            int g = c_ ? gB : gA;
            int esl = g % 3, b = g / 3;
            float f = features[b * NQ + q];
            float s, c; sincosf(0.5f * f, &s, &c);
            if (esl == 0)      { a0 = make_float2(c, 0.f); a1 = make_float2(0.f, -s); }
            else if (esl == 1) { a0 = make_float2(c, 0.f); a1 = make_float2(s, 0.f); }
            else               { a0 = make_float2((c-s)*r_, 0.f); a1 = make_float2((c+s)*r_, 0.f); }
        }
        enc[c_ * NQ + q][0] = a0; enc[c_ * NQ + q][1] = a1;
    }
    __syncthreads();

    // ---- stage 2: fused U = RZ*RY*RX + pair tables ----
    if (tid < NL * NQ) {
        float c0 = cs[tid*3+0].x, s0 = cs[tid*3+0].y;
        float c1 = cs[tid*3+1].x, s1 = cs[tid*3+1].y;
        float c2 = cs[tid*3+2].x, s2 = cs[tid*3+2].y;
        float2 a00 = make_float2( c1*c0,  s1*s0);
        float2 a01 = make_float2(-s1*c0, -c1*s0);
        float2 a10 = make_float2( s1*c0, -c1*s0);
        float2 a11 = make_float2( c1*c0, -s1*s0);
        float2 ep = make_float2(c2, -s2), em = make_float2(c2, s2);
        U48[tid][0] = cmulS(ep, a00); U48[tid][1] = cmulS(ep, a01);
        U48[tid][2] = cmulS(em, a10); U48[tid][3] = cmulS(em, a11);
    }
    if (tid >= 64 && tid < 112) {
        int x = tid - 64;
        int c_ = x / 24, y = x % 24, p = y >> 2, v = y & 3;
        pairT[c_ * 6 + p][v] = cmulS(enc[c_*NQ + 2*p][v >> 1], enc[c_*NQ + 2*p + 1][v & 1]);
    }
    __syncthreads();

    // ---- stage 3: packed SU(2) coeff quads + local product table ----
    for (int idx = tid; idx < 384; idx += THREADS) {
        int p = idx >> 4, rest = idx & 15, c = rest >> 2, comp = rest & 3;
        int l = p / 6, m = p % 6;
        int q = (c < 2) ? (2*m + 1) : (2*m);       // c0,c1: lo qubit; c2,c3: hi qubit
        float2 u = U48[l*NQ + q][c & 1];           // col 0 = a(u00), col 1 = b(u01)
        float xv = (comp == 0) ? u.x : (comp == 1) ? u.y : (comp == 2) ? -u.y : -u.x;
        v2f vv = {xv, xv};
        Upk[p][c][comp] = vv;
    }
    if (tid >= 192 && tid < 224) {
        int x = tid - 192; int c_ = x >> 4, j = x & 15;
        loc[c_ * 16 + j] = cmulS(pairT[c_*6 + 4][j >> 2], pairT[c_*6 + 5][j & 3]);
    }
    __syncthreads();

    // ---- build product state directly into window-A registers (i = tid<<4 | j) ----
    v2f sre[16], sim[16];
    {
        int t = tid;
        float2 preA = cmulS(cmulS(pairT[0][(t>>6)&3], pairT[1][(t>>4)&3]),
                            cmulS(pairT[2][(t>>2)&3], pairT[3][t&3]));
        float2 preB = cmulS(cmulS(pairT[6][(t>>6)&3], pairT[7][(t>>4)&3]),
                            cmulS(pairT[8][(t>>2)&3], pairT[9][t&3]));
        #pragma unroll
        for (int j = 0; j < 16; ++j) {
            float2 aA = cmulS(preA, loc[j]);
            float2 aB = cmulS(preB, loc[16 + j]);
            v2f r = {aA.x, aB.x}, ii = {aA.y, aB.y};
            sre[j] = r; sim[j] = ii;
        }
    }

    // per-thread window bases (amp units), both parities, pre-swizzled
    const int baseA = tid << 4;
    const int baseB = ((tid & 0xF0) << 4) | (tid & 15);
    const int baseC = tid;
    const int AB0[3] = { swz(baseA), swz(baseB), swz(baseC) };
    const int AB1[3] = { swz(sigp(baseA)), swz(sigp(baseB)), swz(sigp(baseC)) };

    // ---- 12 fused hyper-window passes (3 per layer), sigma folded into addressing ----
    #pragma unroll
    for (int l = 0; l < NL; ++l) {
        const int par = l & 1;
        #pragma unroll
        for (int w = 0; w < 3; ++w) {
            const int S = 4 * w;
            const int hx = l*6 + (4 - 2*w);     // hi pair coeff index; lo = hx+1
            int addr[16];
            // address calc + (except the fused first pass) gather, quad-major order
            #pragma unroll
            for (int jj = 0; jj < 16; ++jj) {
                const int j = ((jj & 3) << 2) | (jj >> 2);   // 0,4,8,12,1,5,9,13,...
                const int cj = par ? swz(sigp(j << S)) : swz(j << S);   // compile-time
                addr[j] = (par ? AB1[w] : AB0[w]) ^ cj;
                if (!(l == 0 && w == 0)) {
                    v4f t = st[addr[j]];
                    v2f r = {t[0], t[1]}, ii = {t[2], t[3]};
                    sre[j] = r; sim[j] = ii;
                }
            }
            pass_hi(sre, sim, Upk[hx]);
            pass_lo(sre, sim, Upk[hx + 1]);
            if (!(l == NL-1 && w == 2)) {       // last pass keeps state in regs for measurement
                #pragma unroll
                for (int j = 0; j < 16; ++j) st[addr[j]] = pack4(sre[j], sim[j]);
                __syncthreads();
            }
        }
    }

    // ---- measurement from window-C regs; final sigma folded into sign indices ----
    v2f s0 = {0.f,0.f}, s1 = {0.f,0.f}, s2 = {0.f,0.f}, s3 = {0.f,0.f}, psum = {0.f,0.f};
    {
        const v2f MONE = {-1.f, -1.f};
        #pragma unroll
        for (int j = 0; j < 16; ++j) {
            v2f p = pkfma(sim[j], sim[j], pkmul(sre[j], sre[j]));
            psum = pkadd(psum, p);
            if (j & 8)                        s0 = pkfma(p, MONE, s0); else s0 = pkadd(s0, p);
            if (j & 4)                        s1 = pkfma(p, MONE, s1); else s1 = pkadd(s1, p);
            if ((((j >> 1) ^ (j >> 2)) & 1))  s2 = pkfma(p, MONE, s2); else s2 = pkadd(s2, p);
            if (j & 1)                        s3 = pkfma(p, MONE, s3); else s3 = pkadd(s3, p);
        }
    }
    v2f vals[12];
    {
        int t = tid;
        int mt = t ^ ((t >> 1) & 0xAA);
        vals[0] = s0; vals[1] = s1; vals[2] = s2; vals[3] = s3;
        vals[4]  = ((t >> 7) & 1)  ? -s3 : s3;
        vals[5]  = ((mt >> 6) & 1) ? -psum : psum;
        vals[6]  = ((mt >> 5) & 1) ? -psum : psum;
        vals[7]  = ((mt >> 4) & 1) ? -psum : psum;
        vals[8]  = ((mt >> 3) & 1) ? -psum : psum;
        vals[9]  = ((mt >> 2) & 1) ? -psum : psum;
        vals[10] = ((mt >> 1) & 1) ? -psum : psum;
        vals[11] = (mt & 1)        ? -psum : psum;
    }
    const int lane = tid & 63, wv = tid >> 6;
    #pragma unroll
    for (int q = 0; q < 12; ++q) {
        v2f v = vals[q];
        #pragma unroll
        for (int mm = 32; mm >= 1; mm >>= 1) {
            v.x += __shfl_xor(v.x, mm, 64);
            v.y += __shfl_xor(v.y, mm, 64);
        }
        if (lane == 0) red[q * 4 + wv] = v;
    }
    __syncthreads();

    if (tid < 12) {
        v2f v = pkadd(pkadd(red[tid*4+0], red[tid*4+1]), pkadd(red[tid*4+2], red[tid*4+3]));
        float A0 = alpha[0], A1 = alpha[1], A2 = alpha[2], A3 = alpha[3];
        float mx = fmaxf(fmaxf(A0, A1), fmaxf(A2, A3));
        float E0 = expf(A0-mx), E1 = expf(A1-mx), E2 = expf(A2-mx), E3 = expf(A3-mx);
        float den = E0 + E1 + E2 + E3;
        if (special) {
            wez[tid] = (E2 / den) * v.x;
        } else {
            int eslA = gA % 3, bA = gA / 3;
            int eslB = gB % 3, bB = gB / 3;
            float wA = ((eslA == 0) ? E0 : (eslA == 1) ? E1 : E3) / den;
            float wB = ((eslB == 0) ? E0 : (eslB == 1) ? E1 : E3) / den;
            atomicAdd(out + bA * NQ + tid, wA * v.x);
            atomicAdd(out + bB * NQ + tid, wB * v.y);
        }
    }
    if (special) {
        __syncthreads();
        for (int bb2 = tid; bb2 < 1024; bb2 += THREADS) {
            #pragma unroll
            for (int q = 0; q < NQ; ++q)
                atomicAdd(out + bb2 * NQ + q, wez[q]);
        }
    }
}

extern "C" void kernel_launch(void* const* d_in, const int* in_sizes, int n_in,
                              void* d_out, int out_size, void* d_ws, size_t ws_size,
                              hipStream_t stream) {
    const float* features = (const float*)d_in[0];
    const float* theta    = (const float*)d_in[1];
    const float* alpha    = (const float*)d_in[2];
    float* out = (float*)d_out;

    hipMemsetAsync(out, 0, (size_t)out_size * sizeof(float), stream);
    // block 0 = shared h_angle_rx circuit; blocks 1..1536 = pairs of regular circuits
    vqc_kernel<<<dim3(1537), THREADS, 0, stream>>>(features, theta, alpha, out);
}

// Round 9
// 125.495 us; speedup vs baseline: 1.1947x; 1.1206x over previous
//
#include <hip/hip_runtime.h>
#include <hip/hip_fp16.h>
#include <math.h>

#define NQ 12
#define DIM 4096
#define NL 4
#define THREADS 256
#define SWZC(e) ((e) ^ (((e) >> 3) & 14) ^ (((e) >> 7) & 15))
#define WAVEFENCE() { __builtin_amdgcn_wave_barrier(); __builtin_amdgcn_sched_barrier(0); }

typedef float v2f __attribute__((ext_vector_type(2)));

__device__ __forceinline__ v2f pkfma(v2f a, v2f b, v2f c) {
    v2f d; asm("v_pk_fma_f32 %0, %1, %2, %3" : "=v"(d) : "v"(a), "v"(b), "v"(c)); return d;
}
__device__ __forceinline__ v2f pkmul(v2f a, v2f b) {
    v2f d; asm("v_pk_mul_f32 %0, %1, %2" : "=v"(d) : "v"(a), "v"(b)); return d;
}
__device__ __forceinline__ v2f pkadd(v2f a, v2f b) {
    v2f d; asm("v_pk_add_f32 %0, %1, %2" : "=v"(d) : "v"(a), "v"(b)); return d;
}
__device__ __forceinline__ float2 cmulS(float2 a, float2 b) {
    return make_float2(fmaf(a.x, b.x, -a.y * b.y), fmaf(a.x, b.y, a.y * b.x));
}

// f16 transit packing: (reA,reB) and (imA,imB) as two half2 in one uint2 (8B)
__device__ __forceinline__ uint2 packh(v2f re, v2f im) {
    __half2 a = __floats2half2_rn(re[0], re[1]);
    __half2 b = __floats2half2_rn(im[0], im[1]);
    uint2 r;
    r.x = __builtin_bit_cast(unsigned int, a);
    r.y = __builtin_bit_cast(unsigned int, b);
    return r;
}
__device__ __forceinline__ void unpackh(uint2 t, v2f* re, v2f* im) {
    float2 fa = __half22float2(__builtin_bit_cast(__half2, t.x));
    float2 fb = __half22float2(__builtin_bit_cast(__half2, t.y));
    v2f r = {fa.x, fa.y}, i = {fb.x, fb.y};
    *re = r; *im = i;
}

struct C4 { v2f r, i, ni, nr; };   // broadcast (re,re),(im,im),(-im,-im),(-re,-re)

#define CMUL4(orE, orI, KR, KNI, KI, xre, xim) \
    { orE = pkfma(KNI, xim, pkmul(KR, xre)); orI = pkfma(KI, xre, pkmul(KR, xim)); }
#define CMAC4(orE, orI, KR, KNI, KI, xre, xim) \
    { orE = pkfma(KR, xre, pkfma(KNI, xim, orE)); orI = pkfma(KR, xim, pkfma(KI, xre, orI)); }

// SU(2) 2-stage 4x4 pair-gate; even-CNOT baked in (outputs C<-y3, D<-y2).
#define QUADBODY(A_, B_, C_, D_) { \
    v2f z0r,z0i,z1r,z1i,z2r,z2i,z3r,z3i; \
    CMUL4(z0r,z0i, la.r, la.ni, la.i, sre[A_], sim[A_]); CMAC4(z0r,z0i, lb.r, lb.ni, lb.i, sre[B_], sim[B_]); \
    CMUL4(z1r,z1i, lb.nr, lb.ni, lb.i, sre[A_], sim[A_]); CMAC4(z1r,z1i, la.r, la.i, la.ni, sre[B_], sim[B_]); \
    CMUL4(z2r,z2i, la.r, la.ni, la.i, sre[C_], sim[C_]); CMAC4(z2r,z2i, lb.r, lb.ni, lb.i, sre[D_], sim[D_]); \
    CMUL4(z3r,z3i, lb.nr, lb.ni, lb.i, sre[C_], sim[C_]); CMAC4(z3r,z3i, la.r, la.i, la.ni, sre[D_], sim[D_]); \
    v2f y0r,y0i,y1r,y1i,y2r,y2i,y3r,y3i; \
    CMUL4(y0r,y0i, ha.r, ha.ni, ha.i, z0r, z0i); CMAC4(y0r,y0i, hb.r, hb.ni, hb.i, z2r, z2i); \
    CMUL4(y1r,y1i, ha.r, ha.ni, ha.i, z1r, z1i); CMAC4(y1r,y1i, hb.r, hb.ni, hb.i, z3r, z3i); \
    CMUL4(y2r,y2i, hb.nr, hb.ni, hb.i, z0r, z0i); CMAC4(y2r,y2i, ha.r, ha.i, ha.ni, z2r, z2i); \
    CMUL4(y3r,y3i, hb.nr, hb.ni, hb.i, z1r, z1i); CMAC4(y3r,y3i, ha.r, ha.i, ha.ni, z3r, z3i); \
    sre[A_]=y0r; sim[A_]=y0i; sre[B_]=y1r; sim[B_]=y1i; \
    sre[C_]=y3r; sim[C_]=y3i; sre[D_]=y2r; sim[D_]=y2i; }

__device__ __forceinline__ void pass_hi(v2f* sre, v2f* sim, const v2f (*U)[4]) {
    C4 la={U[0][0],U[0][1],U[0][2],U[0][3]}, lb={U[1][0],U[1][1],U[1][2],U[1][3]},
       ha={U[2][0],U[2][1],U[2][2],U[2][3]}, hb={U[3][0],U[3][1],U[3][2],U[3][3]};
    QUADBODY(0,4,8,12) QUADBODY(1,5,9,13) QUADBODY(2,6,10,14) QUADBODY(3,7,11,15)
}
__device__ __forceinline__ void pass_lo(v2f* sre, v2f* sim, const v2f (*U)[4]) {
    C4 la={U[0][0],U[0][1],U[0][2],U[0][3]}, lb={U[1][0],U[1][1],U[1][2],U[1][3]},
       ha={U[2][0],U[2][1],U[2][2],U[2][3]}, hb={U[3][0],U[3][1],U[3][2],U[3][3]};
    QUADBODY(0,1,2,3) QUADBODY(4,5,6,7) QUADBODY(8,9,10,11) QUADBODY(12,13,14,15)
}

__global__ __attribute__((amdgpu_flat_work_group_size(256, 256), amdgpu_waves_per_eu(2, 8)))
void vqc_kernel(const float* __restrict__ features,
                const float* __restrict__ theta,
                const float* __restrict__ alpha,
                float* __restrict__ out)
{
    __shared__ uint2 scrH[DIM];           // 32 KB f16-packed transit (reA,reB,imA,imB)
    __shared__ v2f Upk[24][4][4];         // 3 KB coeff quads (f32 broadcast)
    __shared__ v2f red[12 * 4];
    __shared__ float wez[12];

    // build-phase tables aliased into scrH (dead before first transition store)
    float2* cs = (float2*)scrH;                                     // [0,1152)
    float2 (*U48)[4] = (float2(*)[4])((char*)scrH + 1152);          // [1152,2688)
    float2 (*enc)[2] = (float2(*)[2])((char*)scrH + 2688);          // [2688,3072)
    float2 (*pairT)[4] = (float2(*)[4])((char*)scrH + 3072);        // [3072,3456)
    float2* loc = (float2*)((char*)scrH + 3456);                    // [3456,3712)

    const int tid = threadIdx.x;
    const bool special = (blockIdx.x == 0);   // shared h_angle_rx circuit (|+>^12 up to phase)
    const int gA = special ? 0 : 2 * ((int)blockIdx.x - 1);
    const int gB = gA + 1;

    // ---- stage 1: theta sincos + encoding states (2 circuits) ----
    if (tid < NL * NQ * 3) {
        float s, c; sincosf(0.5f * theta[tid], &s, &c);
        cs[tid] = make_float2(c, s);
    }
    if (tid >= 160 && tid < 184) {
        int c_ = (tid - 160) / 12, q = (tid - 160) % 12;
        const float r_ = 0.70710678118654752f;
        float2 a0, a1;
        if (special) { a0 = make_float2(r_, 0.f); a1 = a0; }
        else {
            int g = c_ ? gB : gA;
            int esl = g % 3, b = g / 3;
            float f = features[b * NQ + q];
            float s, c; sincosf(0.5f * f, &s, &c);
            if (esl == 0)      { a0 = make_float2(c, 0.f); a1 = make_float2(0.f, -s); }
            else if (esl == 1) { a0 = make_float2(c, 0.f); a1 = make_float2(s, 0.f); }
            else               { a0 = make_float2((c-s)*r_, 0.f); a1 = make_float2((c+s)*r_, 0.f); }
        }
        enc[c_ * NQ + q][0] = a0; enc[c_ * NQ + q][1] = a1;
    }
    __syncthreads();

    // ---- stage 2: fused U = RZ*RY*RX + pair tables ----
    if (tid < NL * NQ) {
        float c0 = cs[tid*3+0].x, s0 = cs[tid*3+0].y;
        float c1 = cs[tid*3+1].x, s1 = cs[tid*3+1].y;
        float c2 = cs[tid*3+2].x, s2 = cs[tid*3+2].y;
        float2 a00 = make_float2( c1*c0,  s1*s0);
        float2 a01 = make_float2(-s1*c0, -c1*s0);
        float2 a10 = make_float2( s1*c0, -c1*s0);
        float2 a11 = make_float2( c1*c0, -s1*s0);
        float2 ep = make_float2(c2, -s2), em = make_float2(c2, s2);
        U48[tid][0] = cmulS(ep, a00); U48[tid][1] = cmulS(ep, a01);
        U48[tid][2] = cmulS(em, a10); U48[tid][3] = cmulS(em, a11);
    }
    if (tid >= 64 && tid < 112) {
        int x = tid - 64;
        int c_ = x / 24, y = x % 24, p = y >> 2, v = y & 3;
        pairT[c_ * 6 + p][v] = cmulS(enc[c_*NQ + 2*p][v >> 1], enc[c_*NQ + 2*p + 1][v & 1]);
    }
    __syncthreads();

    // ---- stage 3: packed SU(2) coeff quads + local product table ----
    for (int idx = tid; idx < 384; idx += THREADS) {
        int p = idx >> 4, rest = idx & 15, c = rest >> 2, comp = rest & 3;
        int l = p / 6, m = p % 6;
        int q = (c < 2) ? (2*m + 1) : (2*m);
        float2 u = U48[l*NQ + q][c & 1];
        float xv = (comp == 0) ? u.x : (comp == 1) ? u.y : (comp == 2) ? -u.y : -u.x;
        v2f vv = {xv, xv};
        Upk[p][c][comp] = vv;
    }
    if (tid >= 192 && tid < 224) {
        int x = tid - 192; int c_ = x >> 4, j = x & 15;
        loc[c_ * 16 + j] = cmulS(pairT[c_*6 + 4][j >> 2], pairT[c_*6 + 5][j & 3]);
    }
    __syncthreads();

    // ---- build product state into LA registers (i = tid<<4 | j) ----
    v2f sre[16], sim[16];
    {
        int t = tid;
        float2 preA = cmulS(cmulS(pairT[0][(t>>6)&3], pairT[1][(t>>4)&3]),
                            cmulS(pairT[2][(t>>2)&3], pairT[3][t&3]));
        float2 preB = cmulS(cmulS(pairT[6][(t>>6)&3], pairT[7][(t>>4)&3]),
                            cmulS(pairT[8][(t>>2)&3], pairT[9][t&3]));
        #pragma unroll
        for (int j = 0; j < 16; ++j) {
            float2 aA = cmulS(preA, loc[j]);
            float2 aB = cmulS(preB, loc[16 + j]);
            v2f r = {aA.x, aB.x}, ii = {aA.y, aB.y};
            sre[j] = r; sim[j] = ii;
        }
    }
    __syncthreads();   // tables (aliased in scrH) dead before first transition store

    const int ba = SWZC(tid << 4);
    const int bb = SWZC((((tid >> 4) << 8) | (tid & 15)));
    const int bc = SWZC(tid);
    const int sx = (tid << 4) ^ ((tid & 1) << 3) ^ (((tid >> 2) & 1) << 5)
                             ^ (((tid >> 4) & 1) << 7) ^ (((tid >> 6) & 1) << 9);
    const int bs = SWZC(sx);

    // ---- 4 variational layers: f16 transit, minimal barrier schedule ----
    #pragma unroll 1
    for (int l = 0; l < NL; ++l) {
        if (l > 0) {
            // LA entry: sigma-folded gather (cross-thread reads of T_CA stores)
            #pragma unroll
            for (int j = 0; j < 16; ++j) {
                int a = bs ^ (j ^ ((j >> 1) & 2));
                unpackh(scrH[a], &sre[j], &sim[j]);
            }
            __syncthreads();   // all gathers done before T_AB overwrites (cross WAR)
        }
        // LA: P4 (bits 3,2), P5 (bits 1,0)
        pass_hi(sre, sim, Upk[l*6 + 4]);
        pass_lo(sre, sim, Upk[l*6 + 5]);
        // T_AB: write own 16-block (ba), read wave-local cross (bb)
        WAVEFENCE();
        #pragma unroll
        for (int j = 0; j < 16; ++j) scrH[ba ^ j] = packh(sre[j], sim[j]);
        WAVEFENCE();
        #pragma unroll
        for (int j = 0; j < 16; ++j) unpackh(scrH[bb ^ SWZC(j << 4)], &sre[j], &sim[j]);
        // LB: P2 (bits 7,6), P3 (bits 5,4)
        pass_hi(sre, sim, Upk[l*6 + 2]);
        pass_lo(sre, sim, Upk[l*6 + 3]);
        // T_BC: write own set (bb), cross gather (bc)
        WAVEFENCE();
        #pragma unroll
        for (int j = 0; j < 16; ++j) scrH[bb ^ SWZC(j << 4)] = packh(sre[j], sim[j]);
        __syncthreads();
        #pragma unroll
        for (int j = 0; j < 16; ++j) unpackh(scrH[bc ^ SWZC(j << 8)], &sre[j], &sim[j]);
        // LC: P0 (bits 11,10), P1 (bits 9,8)
        pass_hi(sre, sim, Upk[l*6 + 0]);
        pass_lo(sre, sim, Upk[l*6 + 1]);
        if (l < NL - 1) {
            // T_CA: write own set (bc); next LA gather is cross -> barrier after
            WAVEFENCE();
            #pragma unroll
            for (int j = 0; j < 16; ++j) scrH[bc ^ SWZC(j << 8)] = packh(sre[j], sim[j]);
            __syncthreads();
        }
    }

    // ---- measurement in LC, layer-3 sigma folded into sign indices ----
    v2f s0 = {0.f,0.f}, s1 = {0.f,0.f}, s2 = {0.f,0.f}, s3 = {0.f,0.f}, psum = {0.f,0.f};
    {
        const v2f MONE = {-1.f, -1.f};
        #pragma unroll
        for (int j = 0; j < 16; ++j) {
            v2f p = pkfma(sim[j], sim[j], pkmul(sre[j], sre[j]));
            psum = pkadd(psum, p);
            if (j & 8)                        s0 = pkfma(p, MONE, s0); else s0 = pkadd(s0, p);
            if (j & 4)                        s1 = pkfma(p, MONE, s1); else s1 = pkadd(s1, p);
            if ((((j >> 1) ^ (j >> 2)) & 1))  s2 = pkfma(p, MONE, s2); else s2 = pkadd(s2, p);
            if (j & 1)                        s3 = pkfma(p, MONE, s3); else s3 = pkadd(s3, p);
        }
    }
    v2f vals[12];
    {
        int t = tid;
        int mt = t ^ ((t >> 1) & 0xAA);
        vals[0] = s0; vals[1] = s1; vals[2] = s2; vals[3] = s3;
        vals[4]  = ((t >> 7) & 1)  ? -s3 : s3;
        vals[5]  = ((mt >> 6) & 1) ? -psum : psum;
        vals[6]  = ((mt >> 5) & 1) ? -psum : psum;
        vals[7]  = ((mt >> 4) & 1) ? -psum : psum;
        vals[8]  = ((mt >> 3) & 1) ? -psum : psum;
        vals[9]  = ((mt >> 2) & 1) ? -psum : psum;
        vals[10] = ((mt >> 1) & 1) ? -psum : psum;
        vals[11] = (mt & 1)        ? -psum : psum;
    }
    const int lane = tid & 63, wv = tid >> 6;
    #pragma unroll
    for (int q = 0; q < 12; ++q) {
        v2f v = vals[q];
        #pragma unroll
        for (int mm = 32; mm >= 1; mm >>= 1) {
            v.x += __shfl_xor(v.x, mm, 64);
            v.y += __shfl_xor(v.y, mm, 64);
        }
        if (lane == 0) red[q * 4 + wv] = v;
    }
    __syncthreads();

    if (tid < 12) {
        v2f v = pkadd(pkadd(red[tid*4+0], red[tid*4+1]), pkadd(red[tid*4+2], red[tid*4+3]));
        float A0 = alpha[0], A1 = alpha[1], A2 = alpha[2], A3 = alpha[3];
        float mx = fmaxf(fmaxf(A0, A1), fmaxf(A2, A3));
        float E0 = expf(A0-mx), E1 = expf(A1-mx), E2 = expf(A2-mx), E3 = expf(A3-mx);
        float den = E0 + E1 + E2 + E3;
        if (special) {
            wez[tid] = (E2 / den) * v.x;
        } else {
            int eslA = gA % 3, bA = gA / 3;
            int eslB = gB % 3, bB = gB / 3;
            float wA = ((eslA == 0) ? E0 : (eslA == 1) ? E1 : E3) / den;
            float wB = ((eslB == 0) ? E0 : (eslB == 1) ? E1 : E3) / den;
            atomicAdd(out + bA * NQ + tid, wA * v.x);
            atomicAdd(out + bB * NQ + tid, wB * v.y);
        }
    }
    if (special) {
        __syncthreads();
        for (int bb2 = tid; bb2 < 1024; bb2 += THREADS) {
            #pragma unroll
            for (int q = 0; q < NQ; ++q)
                atomicAdd(out + bb2 * NQ + q, wez[q]);
        }
    }
}

extern "C" void kernel_launch(void* const* d_in, const int* in_sizes, int n_in,
                              void* d_out, int out_size, void* d_ws, size_t ws_size,
                              hipStream_t stream) {
    const float* features = (const float*)d_in[0];
    const float* theta    = (const float*)d_in[1];
    const float* alpha    = (const float*)d_in[2];
    float* out = (float*)d_out;

    hipMemsetAsync(out, 0, (size_t)out_size * sizeof(float), stream);
    vqc_kernel<<<dim3(1537), THREADS, 0, stream>>>(features, theta, alpha, out);
}

// Round 10
// 125.421 us; speedup vs baseline: 1.1954x; 1.0006x over previous
//
#include <hip/hip_runtime.h>
#include <hip/hip_fp16.h>
#include <math.h>

#define NQ 12
#define DIM 4096
#define NL 4
#define THREADS 256
#define LDSPAD 800   // pads scrH so block LDS lands in (40.96 KB, 54.6 KB] -> exactly 3 blocks/CU
#define SWZC(e) ((e) ^ (((e) >> 3) & 14) ^ (((e) >> 7) & 15))
#define WAVEFENCE() { __builtin_amdgcn_wave_barrier(); __builtin_amdgcn_sched_barrier(0); }

typedef float v2f __attribute__((ext_vector_type(2)));

__device__ __forceinline__ v2f pkfma(v2f a, v2f b, v2f c) {
    v2f d; asm("v_pk_fma_f32 %0, %1, %2, %3" : "=v"(d) : "v"(a), "v"(b), "v"(c)); return d;
}
__device__ __forceinline__ v2f pkmul(v2f a, v2f b) {
    v2f d; asm("v_pk_mul_f32 %0, %1, %2" : "=v"(d) : "v"(a), "v"(b)); return d;
}
__device__ __forceinline__ v2f pkadd(v2f a, v2f b) {
    v2f d; asm("v_pk_add_f32 %0, %1, %2" : "=v"(d) : "v"(a), "v"(b)); return d;
}
__device__ __forceinline__ float2 cmulS(float2 a, float2 b) {
    return make_float2(fmaf(a.x, b.x, -a.y * b.y), fmaf(a.x, b.y, a.y * b.x));
}

// f16 transit packing: (reA,reB) and (imA,imB) as two half2 in one uint2 (8B)
__device__ __forceinline__ uint2 packh(v2f re, v2f im) {
    __half2 a = __floats2half2_rn(re[0], re[1]);
    __half2 b = __floats2half2_rn(im[0], im[1]);
    uint2 r;
    r.x = __builtin_bit_cast(unsigned int, a);
    r.y = __builtin_bit_cast(unsigned int, b);
    return r;
}
__device__ __forceinline__ void unpackh(uint2 t, v2f* re, v2f* im) {
    float2 fa = __half22float2(__builtin_bit_cast(__half2, t.x));
    float2 fb = __half22float2(__builtin_bit_cast(__half2, t.y));
    v2f r = {fa.x, fa.y}, i = {fb.x, fb.y};
    *re = r; *im = i;
}

struct C4 { v2f r, i, ni, nr; };   // broadcast (re,re),(im,im),(-im,-im),(-re,-re)

#define CMUL4(orE, orI, KR, KNI, KI, xre, xim) \
    { orE = pkfma(KNI, xim, pkmul(KR, xre)); orI = pkfma(KI, xre, pkmul(KR, xim)); }
#define CMAC4(orE, orI, KR, KNI, KI, xre, xim) \
    { orE = pkfma(KR, xre, pkfma(KNI, xim, orE)); orI = pkfma(KR, xim, pkfma(KI, xre, orI)); }

// SU(2) 2-stage 4x4 pair-gate; even-CNOT baked in (outputs C<-y3, D<-y2).
#define QUADBODY(A_, B_, C_, D_) { \
    v2f z0r,z0i,z1r,z1i,z2r,z2i,z3r,z3i; \
    CMUL4(z0r,z0i, la.r, la.ni, la.i, sre[A_], sim[A_]); CMAC4(z0r,z0i, lb.r, lb.ni, lb.i, sre[B_], sim[B_]); \
    CMUL4(z1r,z1i, lb.nr, lb.ni, lb.i, sre[A_], sim[A_]); CMAC4(z1r,z1i, la.r, la.i, la.ni, sre[B_], sim[B_]); \
    CMUL4(z2r,z2i, la.r, la.ni, la.i, sre[C_], sim[C_]); CMAC4(z2r,z2i, lb.r, lb.ni, lb.i, sre[D_], sim[D_]); \
    CMUL4(z3r,z3i, lb.nr, lb.ni, lb.i, sre[C_], sim[C_]); CMAC4(z3r,z3i, la.r, la.i, la.ni, sre[D_], sim[D_]); \
    v2f y0r,y0i,y1r,y1i,y2r,y2i,y3r,y3i; \
    CMUL4(y0r,y0i, ha.r, ha.ni, ha.i, z0r, z0i); CMAC4(y0r,y0i, hb.r, hb.ni, hb.i, z2r, z2i); \
    CMUL4(y1r,y1i, ha.r, ha.ni, ha.i, z1r, z1i); CMAC4(y1r,y1i, hb.r, hb.ni, hb.i, z3r, z3i); \
    CMUL4(y2r,y2i, hb.nr, hb.ni, hb.i, z0r, z0i); CMAC4(y2r,y2i, ha.r, ha.i, ha.ni, z2r, z2i); \
    CMUL4(y3r,y3i, hb.nr, hb.ni, hb.i, z1r, z1i); CMAC4(y3r,y3i, ha.r, ha.i, ha.ni, z3r, z3i); \
    sre[A_]=y0r; sim[A_]=y0i; sre[B_]=y1r; sim[B_]=y1i; \
    sre[C_]=y3r; sim[C_]=y3i; sre[D_]=y2r; sim[D_]=y2i; }

__device__ __forceinline__ void pass_hi(v2f* sre, v2f* sim, const v2f (*U)[4]) {
    C4 la={U[0][0],U[0][1],U[0][2],U[0][3]}, lb={U[1][0],U[1][1],U[1][2],U[1][3]},
       ha={U[2][0],U[2][1],U[2][2],U[2][3]}, hb={U[3][0],U[3][1],U[3][2],U[3][3]};
    QUADBODY(0,4,8,12) QUADBODY(1,5,9,13) QUADBODY(2,6,10,14) QUADBODY(3,7,11,15)
}
__device__ __forceinline__ void pass_lo(v2f* sre, v2f* sim, const v2f (*U)[4]) {
    C4 la={U[0][0],U[0][1],U[0][2],U[0][3]}, lb={U[1][0],U[1][1],U[1][2],U[1][3]},
       ha={U[2][0],U[2][1],U[2][2],U[2][3]}, hb={U[3][0],U[3][1],U[3][2],U[3][3]};
    QUADBODY(0,1,2,3) QUADBODY(4,5,6,7) QUADBODY(8,9,10,11) QUADBODY(12,13,14,15)
}

__global__ __launch_bounds__(THREADS, 3)
void vqc_kernel(const float* __restrict__ features,
                const float* __restrict__ theta,
                const float* __restrict__ alpha,
                float* __restrict__ out)
{
    __shared__ uint2 scrH[DIM + LDSPAD];  // 38.9 KB: f16-packed transit + residency pad
    __shared__ v2f Upk[24][4][4];         // 3 KB coeff quads (f32 broadcast)
    __shared__ v2f red[12 * 4];
    __shared__ float wez[12];

    // build-phase tables aliased into scrH (dead before first transition store)
    float2* cs = (float2*)scrH;                                     // [0,1152)
    float2 (*U48)[4] = (float2(*)[4])((char*)scrH + 1152);          // [1152,2688)
    float2 (*enc)[2] = (float2(*)[2])((char*)scrH + 2688);          // [2688,3072)
    float2 (*pairT)[4] = (float2(*)[4])((char*)scrH + 3072);        // [3072,3456)
    float2* loc = (float2*)((char*)scrH + 3456);                    // [3456,3712)

    const int tid = threadIdx.x;
    const bool special = (blockIdx.x == 0);   // shared h_angle_rx circuit (|+>^12 up to phase)
    const int gA = special ? 0 : 2 * ((int)blockIdx.x - 1);
    const int gB = gA + 1;

    // ---- stage 1: theta sincos + encoding states (2 circuits) ----
    if (tid < NL * NQ * 3) {
        float s, c; sincosf(0.5f * theta[tid], &s, &c);
        cs[tid] = make_float2(c, s);
    }
    if (tid >= 160 && tid < 184) {
        int c_ = (tid - 160) / 12, q = (tid - 160) % 12;
        const float r_ = 0.70710678118654752f;
        float2 a0, a1;
        if (special) { a0 = make_float2(r_, 0.f); a1 = a0; }
        else {
            int g = c_ ? gB : gA;
            int esl = g % 3, b = g / 3;
            float f = features[b * NQ + q];
            float s, c; sincosf(0.5f * f, &s, &c);
            if (esl == 0)      { a0 = make_float2(c, 0.f); a1 = make_float2(0.f, -s); }
            else if (esl == 1) { a0 = make_float2(c, 0.f); a1 = make_float2(s, 0.f); }
            else               { a0 = make_float2((c-s)*r_, 0.f); a1 = make_float2((c+s)*r_, 0.f); }
        }
        enc[c_ * NQ + q][0] = a0; enc[c_ * NQ + q][1] = a1;
    }
    __syncthreads();

    // ---- stage 2: fused U = RZ*RY*RX + pair tables ----
    if (tid < NL * NQ) {
        float c0 = cs[tid*3+0].x, s0 = cs[tid*3+0].y;
        float c1 = cs[tid*3+1].x, s1 = cs[tid*3+1].y;
        float c2 = cs[tid*3+2].x, s2 = cs[tid*3+2].y;
        float2 a00 = make_float2( c1*c0,  s1*s0);
        float2 a01 = make_float2(-s1*c0, -c1*s0);
        float2 a10 = make_float2( s1*c0, -c1*s0);
        float2 a11 = make_float2( c1*c0, -s1*s0);
        float2 ep = make_float2(c2, -s2), em = make_float2(c2, s2);
        U48[tid][0] = cmulS(ep, a00); U48[tid][1] = cmulS(ep, a01);
        U48[tid][2] = cmulS(em, a10); U48[tid][3] = cmulS(em, a11);
    }
    if (tid >= 64 && tid < 112) {
        int x = tid - 64;
        int c_ = x / 24, y = x % 24, p = y >> 2, v = y & 3;
        pairT[c_ * 6 + p][v] = cmulS(enc[c_*NQ + 2*p][v >> 1], enc[c_*NQ + 2*p + 1][v & 1]);
    }
    __syncthreads();

    // ---- stage 3: packed SU(2) coeff quads + local product table ----
    for (int idx = tid; idx < 384; idx += THREADS) {
        int p = idx >> 4, rest = idx & 15, c = rest >> 2, comp = rest & 3;
        int l = p / 6, m = p % 6;
        int q = (c < 2) ? (2*m + 1) : (2*m);
        float2 u = U48[l*NQ + q][c & 1];
        float xv = (comp == 0) ? u.x : (comp == 1) ? u.y : (comp == 2) ? -u.y : -u.x;
        v2f vv = {xv, xv};
        Upk[p][c][comp] = vv;
    }
    if (tid >= 192 && tid < 224) {
        int x = tid - 192; int c_ = x >> 4, j = x & 15;
        loc[c_ * 16 + j] = cmulS(pairT[c_*6 + 4][j >> 2], pairT[c_*6 + 5][j & 3]);
    }
    __syncthreads();

    // ---- build product state into LA registers (i = tid<<4 | j) ----
    v2f sre[16], sim[16];
    {
        int t = tid;
        float2 preA = cmulS(cmulS(pairT[0][(t>>6)&3], pairT[1][(t>>4)&3]),
                            cmulS(pairT[2][(t>>2)&3], pairT[3][t&3]));
        float2 preB = cmulS(cmulS(pairT[6][(t>>6)&3], pairT[7][(t>>4)&3]),
                            cmulS(pairT[8][(t>>2)&3], pairT[9][t&3]));
        #pragma unroll
        for (int j = 0; j < 16; ++j) {
            float2 aA = cmulS(preA, loc[j]);
            float2 aB = cmulS(preB, loc[16 + j]);
            v2f r = {aA.x, aB.x}, ii = {aA.y, aB.y};
            sre[j] = r; sim[j] = ii;
        }
    }
    __syncthreads();   // tables (aliased in scrH) dead before first transition store

    const int ba = SWZC(tid << 4);
    const int bb = SWZC((((tid >> 4) << 8) | (tid & 15)));
    const int bc = SWZC(tid);
    const int sx = (tid << 4) ^ ((tid & 1) << 3) ^ (((tid >> 2) & 1) << 5)
                             ^ (((tid >> 4) & 1) << 7) ^ (((tid >> 6) & 1) << 9);
    const int bs = SWZC(sx);

    // ---- 4 variational layers: f16 transit, minimal barrier schedule ----
    #pragma unroll 1
    for (int l = 0; l < NL; ++l) {
        if (l > 0) {
            // LA entry: sigma-folded gather (cross-thread reads of T_CA stores)
            #pragma unroll
            for (int j = 0; j < 16; ++j) {
                int a = bs ^ (j ^ ((j >> 1) & 2));
                unpackh(scrH[a], &sre[j], &sim[j]);
            }
            __syncthreads();   // all gathers done before T_AB overwrites (cross WAR)
        }
        // LA: P4 (bits 3,2), P5 (bits 1,0)
        pass_hi(sre, sim, Upk[l*6 + 4]);
        pass_lo(sre, sim, Upk[l*6 + 5]);
        // T_AB: write own 16-block (ba), read wave-local cross (bb)
        WAVEFENCE();
        #pragma unroll
        for (int j = 0; j < 16; ++j) scrH[ba ^ j] = packh(sre[j], sim[j]);
        WAVEFENCE();
        #pragma unroll
        for (int j = 0; j < 16; ++j) unpackh(scrH[bb ^ SWZC(j << 4)], &sre[j], &sim[j]);
        // LB: P2 (bits 7,6), P3 (bits 5,4)
        pass_hi(sre, sim, Upk[l*6 + 2]);
        pass_lo(sre, sim, Upk[l*6 + 3]);
        // T_BC: write own set (bb), cross gather (bc)
        WAVEFENCE();
        #pragma unroll
        for (int j = 0; j < 16; ++j) scrH[bb ^ SWZC(j << 4)] = packh(sre[j], sim[j]);
        __syncthreads();
        #pragma unroll
        for (int j = 0; j < 16; ++j) unpackh(scrH[bc ^ SWZC(j << 8)], &sre[j], &sim[j]);
        // LC: P0 (bits 11,10), P1 (bits 9,8)
        pass_hi(sre, sim, Upk[l*6 + 0]);
        pass_lo(sre, sim, Upk[l*6 + 1]);
        if (l < NL - 1) {
            // T_CA: write own set (bc); next LA gather is cross -> barrier after
            WAVEFENCE();
            #pragma unroll
            for (int j = 0; j < 16; ++j) scrH[bc ^ SWZC(j << 8)] = packh(sre[j], sim[j]);
            __syncthreads();
        }
    }

    // ---- measurement in LC, layer-3 sigma folded into sign indices ----
    v2f s0 = {0.f,0.f}, s1 = {0.f,0.f}, s2 = {0.f,0.f}, s3 = {0.f,0.f}, psum = {0.f,0.f};
    {
        const v2f MONE = {-1.f, -1.f};
        #pragma unroll
        for (int j = 0; j < 16; ++j) {
            v2f p = pkfma(sim[j], sim[j], pkmul(sre[j], sre[j]));
            psum = pkadd(psum, p);
            if (j & 8)                        s0 = pkfma(p, MONE, s0); else s0 = pkadd(s0, p);
            if (j & 4)                        s1 = pkfma(p, MONE, s1); else s1 = pkadd(s1, p);
            if ((((j >> 1) ^ (j >> 2)) & 1))  s2 = pkfma(p, MONE, s2); else s2 = pkadd(s2, p);
            if (j & 1)                        s3 = pkfma(p, MONE, s3); else s3 = pkadd(s3, p);
        }
    }
    v2f vals[12];
    {
        int t = tid;
        int mt = t ^ ((t >> 1) & 0xAA);
        vals[0] = s0; vals[1] = s1; vals[2] = s2; vals[3] = s3;
        vals[4]  = ((t >> 7) & 1)  ? -s3 : s3;
        vals[5]  = ((mt >> 6) & 1) ? -psum : psum;
        vals[6]  = ((mt >> 5) & 1) ? -psum : psum;
        vals[7]  = ((mt >> 4) & 1) ? -psum : psum;
        vals[8]  = ((mt >> 3) & 1) ? -psum : psum;
        vals[9]  = ((mt >> 2) & 1) ? -psum : psum;
        vals[10] = ((mt >> 1) & 1) ? -psum : psum;
        vals[11] = (mt & 1)        ? -psum : psum;
    }
    const int lane = tid & 63, wv = tid >> 6;
    #pragma unroll
    for (int q = 0; q < 12; ++q) {
        v2f v = vals[q];
        #pragma unroll
        for (int mm = 32; mm >= 1; mm >>= 1) {
            v.x += __shfl_xor(v.x, mm, 64);
            v.y += __shfl_xor(v.y, mm, 64);
        }
        if (lane == 0) red[q * 4 + wv] = v;
    }
    __syncthreads();

    if (tid < 12) {
        v2f v = pkadd(pkadd(red[tid*4+0], red[tid*4+1]), pkadd(red[tid*4+2], red[tid*4+3]));
        float A0 = alpha[0], A1 = alpha[1], A2 = alpha[2], A3 = alpha[3];
        float mx = fmaxf(fmaxf(A0, A1), fmaxf(A2, A3));
        float E0 = expf(A0-mx), E1 = expf(A1-mx), E2 = expf(A2-mx), E3 = expf(A3-mx);
        float den = E0 + E1 + E2 + E3;
        if (special) {
            wez[tid] = (E2 / den) * v.x;
        } else {
            int eslA = gA % 3, bA = gA / 3;
            int eslB = gB % 3, bB = gB / 3;
            float wA = ((eslA == 0) ? E0 : (eslA == 1) ? E1 : E3) / den;
            float wB = ((eslB == 0) ? E0 : (eslB == 1) ? E1 : E3) / den;
            atomicAdd(out + bA * NQ + tid, wA * v.x);
            atomicAdd(out + bB * NQ + tid, wB * v.y);
        }
    }
    if (special) {
        __syncthreads();
        for (int bb2 = tid; bb2 < 1024; bb2 += THREADS) {
            #pragma unroll
            for (int q = 0; q < NQ; ++q)
                atomicAdd(out + bb2 * NQ + q, wez[q]);
        }
    }
}

extern "C" void kernel_launch(void* const* d_in, const int* in_sizes, int n_in,
                              void* d_out, int out_size, void* d_ws, size_t ws_size,
                              hipStream_t stream) {
    const float* features = (const float*)d_in[0];
    const float* theta    = (const float*)d_in[1];
    const float* alpha    = (const float*)d_in[2];
    float* out = (float*)d_out;

    hipMemsetAsync(out, 0, (size_t)out_size * sizeof(float), stream);
    vqc_kernel<<<dim3(1537), THREADS, 0, stream>>>(features, theta, alpha, out);
}